// Round 19
// baseline (27.735 us; speedup 1.0000x reference)
//
#include <hip/hip_runtime.h>

// ============================================================================
// PGALoss, analytically reduced:
//   per-point loss = sqrt(1 + d^2) + d,  d = NN distance
//   out = 0.5 * sum_dir clip((mean loss - 1)/2, 0, 1)
// d^2 = min_p(||p||^2 - 2 q.p) + ||q||^2   via bf16 hi/lo-split MFMA
//
// R19: R16 skeleton, PS=16 (512 pts/block, LDS 18.4KB) -> 8 blocks/CU =
// 32 waves/CU (max) for latency hiding; rocprof has a ~39us per-dispatch
// floor so bench dur_us is the only signal. Round-to-nearest bf16 split
// restored (absmax 0.0; truncation bought nothing).
// ============================================================================

typedef short short8 __attribute__((ext_vector_type(8)));
typedef float f32x16 __attribute__((ext_vector_type(16)));

#define PPB      512             // points per block
#define PS       16              // point chunks (N/PPB)
#define NTILE    16              // PPB/32
#define LDS_HALF 576             // 32 rows * 16B + 4 * 16B pad
#define LDS_TILE 1152            // two k-halves

// ws layout (memset 0x7f covers [0, 2048 + 4*QT)):
//   [0,512)     chunkCnt[128] u32   (init 0x7f7f7f7f)
//   [512,516)   finalCnt u32        (init 0x7f7f7f7f)
//   [1024,1536) accP[128] u32       (atomicExch-written float bits)
//   [2048,...)  d2min[QT] u32       (init 0x7f7f7f7f = +huge)

__device__ __forceinline__ unsigned short bf16h(float f) {
    unsigned u = __float_as_uint(f);
    return (unsigned short)((u + 0x7fffu + ((u >> 16) & 1u)) >> 16);
}
__device__ __forceinline__ float bf16v(unsigned short h) {
    return __uint_as_float((unsigned)h << 16);
}

__global__ __launch_bounds__(256, 8)
void fused_kernel(const float* __restrict__ src, const float* __restrict__ tgt,
                  unsigned* __restrict__ chunkCnt, unsigned* __restrict__ finalCnt,
                  unsigned* __restrict__ accP, unsigned* __restrict__ d2min,
                  float* __restrict__ out, int N) {
    __shared__ __align__(16) unsigned char Alds[NTILE * LDS_TILE];  // 18.4 KB

    const int t   = threadIdx.x;
    const int l   = t & 63, w = t >> 6;
    const int nqc = N >> 8;                  // 32 query chunks (256 q each)
    const int bpt = nqc * PS;                // 512 blocks per task
    const int task = blockIdx.x / bpt;       // 0..3 = s0,s1,t0,t1
    const int rem  = blockIdx.x % bpt;
    const int qc = rem / PS, pc = rem % PS;

    // ---- A-prep: 512 points of cloud (task^2), chunk pc -> LDS ----
    // thread t preps points 2t,2t+1 via 3 float2 loads (24 contiguous bytes)
    const int pcloud = task ^ 2;
    const float* pRaw = (pcloud < 2 ? src : tgt)
                        + (size_t)3 * ((size_t)(pcloud & 1) * N + (size_t)pc * PPB);
    {
        const float2* p2 = (const float2*)pRaw + (size_t)3 * t;
        const float2 v0 = p2[0], v1 = p2[1], v2 = p2[2];
        float P[2][3] = {{v0.x, v0.y, v1.x}, {v1.y, v2.x, v2.y}};
        #pragma unroll
        for (int e = 0; e < 2; ++e) {
            const int j = 2 * t + e;
            const float x = P[e][0], y = P[e][1], z = P[e][2];
            const float pp = x*x + y*y + z*z;
            unsigned short A16[16];
            #pragma unroll
            for (int d = 0; d < 3; ++d) {
                const float m2 = -2.0f * P[e][d];
                const unsigned short th = bf16h(m2);
                A16[d] = th; A16[4+d] = th;
                A16[8+d] = bf16h(m2 - bf16v(th));
            }
            const unsigned short pph = bf16h(pp);
            A16[3] = pph; A16[7] = bf16h(pp - bf16v(pph)); A16[11] = 0;
            A16[12] = A16[13] = A16[14] = A16[15] = 0;
            const int tile = j >> 5, r = j & 31;
            unsigned char* base = Alds + tile * LDS_TILE + r * 16 + (r >> 3) * 16;
            *(short8*)(base)            = *(const short8*)(A16);
            *(short8*)(base + LDS_HALF) = *(const short8*)(A16 + 8);
        }
    }

    // ---- B-fragments in registers ----
    const int col = l & 31, h = l >> 5;
    const float* qRaw = (task < 2 ? src : tgt)
                        + (size_t)3 * (size_t)((task & 1) * N);
    const int qloc = qc * 256 + w * 64 + col;
    float qa[3], qb[3];
    #pragma unroll
    for (int d = 0; d < 3; ++d) {
        qa[d] = qRaw[3*qloc + d];
        qb[d] = qRaw[3*(qloc+32) + d];
    }
    const float qqa = qa[0]*qa[0] + qa[1]*qa[1] + qa[2]*qa[2];
    const float qqb = qb[0]*qb[0] + qb[1]*qb[1] + qb[2]*qb[2];

    unsigned short B0[8], B1[8];
    #pragma unroll
    for (int d = 0; d < 3; ++d) {
        const unsigned short ha = bf16h(qa[d]);
        const unsigned short hb = bf16h(qb[d]);
        B0[d] = ha; B1[d] = hb;
        B0[4+d] = (h == 0) ? bf16h(qa[d] - bf16v(ha)) : (unsigned short)0;
        B1[4+d] = (h == 0) ? bf16h(qb[d] - bf16v(hb)) : (unsigned short)0;
    }
    B0[3] = B0[7] = (h == 0) ? (unsigned short)0x3F80 : (unsigned short)0;
    B1[3] = B1[7] = B0[3];
    const short8 b0 = *(const short8*)B0;
    const short8 b1 = *(const short8*)B1;

    __syncthreads();

    // ---- MFMA loop over 16 tiles ----
    const int lbase = h * LDS_HALF + col * 16 + (col >> 3) * 16;
    float best0 = 3.4e38f, best1 = 3.4e38f;
    const f32x16 zero = {};
    #pragma unroll 4
    for (int i = 0; i < NTILE; ++i) {
        const short8 a = *(const short8*)(Alds + i * LDS_TILE + lbase);
        f32x16 d0 = __builtin_amdgcn_mfma_f32_32x32x16_bf16(a, b0, zero, 0, 0, 0);
        f32x16 d1 = __builtin_amdgcn_mfma_f32_32x32x16_bf16(a, b1, zero, 0, 0, 0);
        best0 = fminf(fminf(d0[0],  d0[1]),  best0);
        best0 = fminf(fminf(d0[2],  d0[3]),  best0);
        best0 = fminf(fminf(d0[4],  d0[5]),  best0);
        best0 = fminf(fminf(d0[6],  d0[7]),  best0);
        best0 = fminf(fminf(d0[8],  d0[9]),  best0);
        best0 = fminf(fminf(d0[10], d0[11]), best0);
        best0 = fminf(fminf(d0[12], d0[13]), best0);
        best0 = fminf(fminf(d0[14], d0[15]), best0);
        best1 = fminf(fminf(d1[0],  d1[1]),  best1);
        best1 = fminf(fminf(d1[2],  d1[3]),  best1);
        best1 = fminf(fminf(d1[4],  d1[5]),  best1);
        best1 = fminf(fminf(d1[6],  d1[7]),  best1);
        best1 = fminf(fminf(d1[8],  d1[9]),  best1);
        best1 = fminf(fminf(d1[10], d1[11]), best1);
        best1 = fminf(fminf(d1[12], d1[13]), best1);
        best1 = fminf(fminf(d1[14], d1[15]), best1);
    }

    // ---- merge + atomicMin (returns consumed -> complete before counter) ----
    best0 = fminf(best0, __shfl_xor(best0, 32));
    best1 = fminf(best1, __shfl_xor(best1, 32));
    const int qbase = task * N + qc * 256;
    if (l < 32) {
        const int q0 = qbase + w * 64 + l;
        unsigned o0 = atomicMin(&d2min[q0],
                                __float_as_uint(fmaxf(best0 + qqa, 0.0f)));
        unsigned o1 = atomicMin(&d2min[q0 + 32],
                                __float_as_uint(fmaxf(best1 + qqb, 0.0f)));
        asm volatile("" :: "v"(o0), "v"(o1));   // forces vmcnt drain
    }

    // ---- chunk-last detection ----
    __shared__ int lastChunk;
    __syncthreads();
    if (t == 0)
        lastChunk = (atomicAdd(&chunkCnt[task * nqc + qc], 1u)
                     == 0x7f7f7f7fu + (unsigned)PS - 1u);
    __syncthreads();
    if (!lastChunk) return;

    // ---- chunk finalize: 256 queries, atomic-coherent reads ----
    const float d2 = __uint_as_float(atomicOr(&d2min[qbase + t], 0u));
    double fv = (double)(sqrtf(1.0f + d2) + sqrtf(d2));
    #pragma unroll
    for (int o = 32; o > 0; o >>= 1) fv += __shfl_down(fv, o);
    __shared__ double wsum[4];
    __shared__ int lastFinal;
    if (l == 0) wsum[w] = fv;
    __syncthreads();
    if (t == 0) {
        const float csum = (float)(wsum[0] + wsum[1] + wsum[2] + wsum[3]);
        unsigned oldA = atomicExch(&accP[task * nqc + qc], __float_as_uint(csum));
        asm volatile("" :: "v"(oldA));          // exch complete at coherence
        lastFinal = (atomicAdd(finalCnt, 1u)
                     == 0x7f7f7f7fu + (unsigned)(4 * nqc) - 1u);
    }
    __syncthreads();
    if (!lastFinal) return;

    // ---- global finalize (exactly one block) ----
    __shared__ float pvals[128];
    const int ncid = 4 * nqc;                    // 128
    if (t < ncid) pvals[t] = __uint_as_float(atomicOr(&accP[t], 0u));
    __syncthreads();
    if (t == 0) {
        double s0 = 0.0, s1 = 0.0;
        for (int i = 0; i < ncid / 2; ++i)        s0 += (double)pvals[i];
        for (int i = ncid / 2; i < ncid; ++i)     s1 += (double)pvals[i];
        const double inv = 1.0 / (double)(2 * N);
        double l0 = (s0 * inv - 1.0) * 0.5;
        double l1 = (s1 * inv - 1.0) * 0.5;
        l0 = l0 < 0.0 ? 0.0 : (l0 > 1.0 ? 1.0 : l0);
        l1 = l1 < 0.0 ? 0.0 : (l1 > 1.0 ? 1.0 : l1);
        out[0] = (float)(0.5 * (l0 + l1));
    }
}

extern "C" void kernel_launch(void* const* d_in, const int* in_sizes, int n_in,
                              void* d_out, int out_size, void* d_ws, size_t ws_size,
                              hipStream_t stream) {
    const float* src = (const float*)d_in[0];
    const float* tgt = (const float*)d_in[1];
    float* out = (float*)d_out;

    const int twoN = in_sizes[0] / 3;    // 16384 points per input
    const int N    = twoN / 2;           // 8192
    const int QT   = 4 * N;              // 32768

    unsigned* chunkCnt = (unsigned*)d_ws;
    unsigned* finalCnt = (unsigned*)((char*)d_ws + 512);
    unsigned* accP     = (unsigned*)((char*)d_ws + 1024);
    unsigned* d2min    = (unsigned*)((char*)d_ws + 2048);

    // one memset node: counters AND d2min (+inf as uint) all 0x7f7f7f7f
    hipMemsetAsync(d_ws, 0x7f, 2048 + (size_t)QT * sizeof(unsigned), stream);

    const int blocks = 4 * (N >> 8) * PS;   // 2048
    fused_kernel<<<blocks, 256, 0, stream>>>(src, tgt, chunkCnt, finalCnt,
                                             accP, d2min, out, N);
}

// Round 20
// 23.821 us; speedup vs baseline: 1.1643x; 1.1643x over previous
//
#include <hip/hip_runtime.h>

// ============================================================================
// PGALoss, analytically reduced:
//   per-point loss = sqrt(1 + d^2) + d,  d = NN distance
//   out = 0.5 * sum_dir clip((mean loss - 1)/2, 0, 1)
// d^2 = min_p(||p||^2 - 2 q.p) + ||q||^2   via bf16 hi/lo-split MFMA
//
// R20: R16/R18 skeleton (proven 24.8us; PS=8, 4 blocks/CU). Changes:
//   - global finalizer: parallel 2-wave shfl reduce (was serial 128 f64 adds)
//   - query loads hoisted ahead of A-prep (overlap independent load streams)
//   - round-to-nearest bf16 split (absmax 0.0; truncation bought nothing)
// Model: ~19us fixed launch/graph overhead + ~2us/node + ~5us kernel.
// ============================================================================

typedef short short8 __attribute__((ext_vector_type(8)));
typedef float f32x16 __attribute__((ext_vector_type(16)));

#define PPB      1024            // points per block
#define PS       8               // point chunks (N/PPB)
#define LDS_HALF 576             // 32 rows * 16B + 4 * 16B pad
#define LDS_TILE 1152            // two k-halves

// ws layout (memset 0x7f covers [0, 2048 + 4*QT)):
//   [0,512)     chunkCnt[128] u32   (init 0x7f7f7f7f)
//   [512,516)   finalCnt u32        (init 0x7f7f7f7f)
//   [1024,1536) accP[128] u32       (atomicExch-written float bits)
//   [2048,...)  d2min[QT] u32       (init 0x7f7f7f7f = +huge)

__device__ __forceinline__ unsigned short bf16h(float f) {
    unsigned u = __float_as_uint(f);
    return (unsigned short)((u + 0x7fffu + ((u >> 16) & 1u)) >> 16);
}
__device__ __forceinline__ float bf16v(unsigned short h) {
    return __uint_as_float((unsigned)h << 16);
}

__global__ __launch_bounds__(256, 4)
void fused_kernel(const float* __restrict__ src, const float* __restrict__ tgt,
                  unsigned* __restrict__ chunkCnt, unsigned* __restrict__ finalCnt,
                  unsigned* __restrict__ accP, unsigned* __restrict__ d2min,
                  float* __restrict__ out, int N) {
    __shared__ __align__(16) unsigned char Alds[32 * LDS_TILE];  // 36 KB

    const int t   = threadIdx.x;
    const int l   = t & 63, w = t >> 6;
    const int nqc = N >> 8;                  // 32 query chunks (256 q each)
    const int bpt = nqc * PS;                // 256 blocks per task
    const int task = blockIdx.x / bpt;       // 0..3 = s0,s1,t0,t1
    const int rem  = blockIdx.x % bpt;
    const int qc = rem / PS, pc = rem % PS;

    // ---- hoisted query loads (independent of point stream) ----
    const int col = l & 31, h = l >> 5;
    const float* qRaw = (task < 2 ? src : tgt)
                        + (size_t)3 * (size_t)((task & 1) * N);
    const int qloc = qc * 256 + w * 64 + col;
    float qa[3], qb[3];
    #pragma unroll
    for (int d = 0; d < 3; ++d) {
        qa[d] = qRaw[3*qloc + d];
        qb[d] = qRaw[3*(qloc+32) + d];
    }

    // ---- A-prep: 1024 points of cloud (task^2), chunk pc -> LDS ----
    // thread t preps points 4t..4t+3 via 3 float4 loads (48 contiguous bytes)
    const int pcloud = task ^ 2;
    const float* pRaw = (pcloud < 2 ? src : tgt)
                        + (size_t)3 * ((size_t)(pcloud & 1) * N + (size_t)pc * PPB);
    {
        const float4* p4 = (const float4*)pRaw + (size_t)3 * t;
        const float4 v0 = p4[0], v1 = p4[1], v2 = p4[2];
        float P[4][3] = {{v0.x, v0.y, v0.z}, {v0.w, v1.x, v1.y},
                         {v1.z, v1.w, v2.x}, {v2.y, v2.z, v2.w}};
        #pragma unroll
        for (int e = 0; e < 4; ++e) {
            const int j = 4 * t + e;
            const float x = P[e][0], y = P[e][1], z = P[e][2];
            const float pp = x*x + y*y + z*z;
            unsigned short A16[16];
            #pragma unroll
            for (int d = 0; d < 3; ++d) {
                const float m2 = -2.0f * P[e][d];
                const unsigned short th = bf16h(m2);
                A16[d] = th; A16[4+d] = th;
                A16[8+d] = bf16h(m2 - bf16v(th));
            }
            const unsigned short pph = bf16h(pp);
            A16[3] = pph; A16[7] = bf16h(pp - bf16v(pph)); A16[11] = 0;
            A16[12] = A16[13] = A16[14] = A16[15] = 0;
            const int tile = j >> 5, r = j & 31;
            unsigned char* base = Alds + tile * LDS_TILE + r * 16 + (r >> 3) * 16;
            *(short8*)(base)            = *(const short8*)(A16);
            *(short8*)(base + LDS_HALF) = *(const short8*)(A16 + 8);
        }
    }

    // ---- B-fragments in registers ----
    const float qqa = qa[0]*qa[0] + qa[1]*qa[1] + qa[2]*qa[2];
    const float qqb = qb[0]*qb[0] + qb[1]*qb[1] + qb[2]*qb[2];

    unsigned short B0[8], B1[8];
    #pragma unroll
    for (int d = 0; d < 3; ++d) {
        const unsigned short ha = bf16h(qa[d]);
        const unsigned short hb = bf16h(qb[d]);
        B0[d] = ha; B1[d] = hb;
        B0[4+d] = (h == 0) ? bf16h(qa[d] - bf16v(ha)) : (unsigned short)0;
        B1[4+d] = (h == 0) ? bf16h(qb[d] - bf16v(hb)) : (unsigned short)0;
    }
    B0[3] = B0[7] = (h == 0) ? (unsigned short)0x3F80 : (unsigned short)0;
    B1[3] = B1[7] = B0[3];
    const short8 b0 = *(const short8*)B0;
    const short8 b1 = *(const short8*)B1;

    __syncthreads();

    // ---- MFMA loop over 32 tiles ----
    const int lbase = h * LDS_HALF + col * 16 + (col >> 3) * 16;
    float best0 = 3.4e38f, best1 = 3.4e38f;
    const f32x16 zero = {};
    #pragma unroll 4
    for (int i = 0; i < 32; ++i) {
        const short8 a = *(const short8*)(Alds + i * LDS_TILE + lbase);
        f32x16 d0 = __builtin_amdgcn_mfma_f32_32x32x16_bf16(a, b0, zero, 0, 0, 0);
        f32x16 d1 = __builtin_amdgcn_mfma_f32_32x32x16_bf16(a, b1, zero, 0, 0, 0);
        best0 = fminf(fminf(d0[0],  d0[1]),  best0);
        best0 = fminf(fminf(d0[2],  d0[3]),  best0);
        best0 = fminf(fminf(d0[4],  d0[5]),  best0);
        best0 = fminf(fminf(d0[6],  d0[7]),  best0);
        best0 = fminf(fminf(d0[8],  d0[9]),  best0);
        best0 = fminf(fminf(d0[10], d0[11]), best0);
        best0 = fminf(fminf(d0[12], d0[13]), best0);
        best0 = fminf(fminf(d0[14], d0[15]), best0);
        best1 = fminf(fminf(d1[0],  d1[1]),  best1);
        best1 = fminf(fminf(d1[2],  d1[3]),  best1);
        best1 = fminf(fminf(d1[4],  d1[5]),  best1);
        best1 = fminf(fminf(d1[6],  d1[7]),  best1);
        best1 = fminf(fminf(d1[8],  d1[9]),  best1);
        best1 = fminf(fminf(d1[10], d1[11]), best1);
        best1 = fminf(fminf(d1[12], d1[13]), best1);
        best1 = fminf(fminf(d1[14], d1[15]), best1);
    }

    // ---- merge + atomicMin (returns consumed -> complete before counter) ----
    best0 = fminf(best0, __shfl_xor(best0, 32));
    best1 = fminf(best1, __shfl_xor(best1, 32));
    const int qbase = task * N + qc * 256;
    if (l < 32) {
        const int q0 = qbase + w * 64 + l;
        unsigned o0 = atomicMin(&d2min[q0],
                                __float_as_uint(fmaxf(best0 + qqa, 0.0f)));
        unsigned o1 = atomicMin(&d2min[q0 + 32],
                                __float_as_uint(fmaxf(best1 + qqb, 0.0f)));
        asm volatile("" :: "v"(o0), "v"(o1));   // forces vmcnt drain
    }

    // ---- chunk-last detection ----
    __shared__ int lastChunk;
    __syncthreads();
    if (t == 0)
        lastChunk = (atomicAdd(&chunkCnt[task * nqc + qc], 1u)
                     == 0x7f7f7f7fu + (unsigned)PS - 1u);
    __syncthreads();
    if (!lastChunk) return;

    // ---- chunk finalize: 256 queries, atomic-coherent reads ----
    const float d2 = __uint_as_float(atomicOr(&d2min[qbase + t], 0u));
    double fv = (double)(sqrtf(1.0f + d2) + sqrtf(d2));
    #pragma unroll
    for (int o = 32; o > 0; o >>= 1) fv += __shfl_down(fv, o);
    __shared__ double wsum[4];
    __shared__ int lastFinal;
    if (l == 0) wsum[w] = fv;
    __syncthreads();
    if (t == 0) {
        const float csum = (float)(wsum[0] + wsum[1] + wsum[2] + wsum[3]);
        unsigned oldA = atomicExch(&accP[task * nqc + qc], __float_as_uint(csum));
        asm volatile("" :: "v"(oldA));          // exch complete at coherence
        lastFinal = (atomicAdd(finalCnt, 1u)
                     == 0x7f7f7f7fu + (unsigned)(4 * nqc) - 1u);
    }
    __syncthreads();
    if (!lastFinal) return;

    // ---- global finalize (one block): parallel 2-wave reduce ----
    const int ncid = 4 * nqc;                    // 128
    double pv0 = 0.0, pv1 = 0.0;
    if (t < ncid) {
        const double v = (double)__uint_as_float(atomicOr(&accP[t], 0u));
        if (t < ncid / 2) pv0 = v; else pv1 = v;  // wave 0: dir0, wave 1: dir1
    }
    #pragma unroll
    for (int o = 32; o > 0; o >>= 1) {
        pv0 += __shfl_down(pv0, o);
        pv1 += __shfl_down(pv1, o);
    }
    __shared__ double fsum[2];
    if (l == 0 && w < 2) fsum[w] = (w == 0) ? pv0 : pv1;
    __syncthreads();
    if (t == 0) {
        const double inv = 1.0 / (double)(2 * N);
        double l0 = (fsum[0] * inv - 1.0) * 0.5;
        double l1 = (fsum[1] * inv - 1.0) * 0.5;
        l0 = l0 < 0.0 ? 0.0 : (l0 > 1.0 ? 1.0 : l0);
        l1 = l1 < 0.0 ? 0.0 : (l1 > 1.0 ? 1.0 : l1);
        out[0] = (float)(0.5 * (l0 + l1));
    }
}

extern "C" void kernel_launch(void* const* d_in, const int* in_sizes, int n_in,
                              void* d_out, int out_size, void* d_ws, size_t ws_size,
                              hipStream_t stream) {
    const float* src = (const float*)d_in[0];
    const float* tgt = (const float*)d_in[1];
    float* out = (float*)d_out;

    const int twoN = in_sizes[0] / 3;    // 16384 points per input
    const int N    = twoN / 2;           // 8192
    const int QT   = 4 * N;              // 32768

    unsigned* chunkCnt = (unsigned*)d_ws;
    unsigned* finalCnt = (unsigned*)((char*)d_ws + 512);
    unsigned* accP     = (unsigned*)((char*)d_ws + 1024);
    unsigned* d2min    = (unsigned*)((char*)d_ws + 2048);

    // one memset node: counters AND d2min (+inf as uint) all 0x7f7f7f7f
    hipMemsetAsync(d_ws, 0x7f, 2048 + (size_t)QT * sizeof(unsigned), stream);

    const int blocks = 4 * (N >> 8) * PS;   // 1024
    fused_kernel<<<blocks, 256, 0, stream>>>(src, tgt, chunkCnt, finalCnt,
                                             accP, d2min, out, N);
}